// Round 13
// baseline (226.365 us; speedup 1.0000x reference)
//
#include <hip/hip_runtime.h>
#include <hip/hip_bf16.h>
#include <stdint.h>

#define NN 16384
#define UU 128
#define CAP 128
#define LCAP 8               // per-lane slot capacity in the scan

typedef unsigned short u16;
typedef unsigned int uv4 __attribute__((ext_vector_type(4)));  // nt-load-able

// Gather-sum of fp32 x-rows listed in sIdx[0..c): 2-way k-parallel (wave
// halves), float4 per lane (32 lanes * 16B = one 512B row per k-slot).
__device__ __forceinline__ float4 gather_row_sum_f32(const float* __restrict__ src,
                                                     const u16* sIdx, int c,
                                                     int half, int sl) {
    float4 acc = {0.f, 0.f, 0.f, 0.f};
#pragma unroll 8
    for (int k = half; k < c; k += 2) {
        const int j = sIdx[k];                                  // LDS broadcast
        const float4 v = *reinterpret_cast<const float4*>(src + (size_t)j * UU + sl * 4);
        acc.x += v.x; acc.y += v.y; acc.z += v.z; acc.w += v.w;
    }
    acc.x += __shfl_xor(acc.x, 32);
    acc.y += __shfl_xor(acc.y, 32);
    acc.z += __shfl_xor(acc.z, 32);
    acc.w += __shfl_xor(acc.w, 32);
    return acc;
}

// ---------------------------------------------------------------------------
// Kernel A: fused sparsify + hop1 + y1-precompute (R12-proven body).
// Launched with 30 KB dynamic LDS to throttle to ~4 blocks/CU: halves the
// number of concurrent HBM row-streams (8192 -> ~4096) to cut DRAM
// row-buffer thrash. In-flight loads stay >> BW*latency product.
// ---------------------------------------------------------------------------
__global__ __launch_bounds__(256) void fused_sparsify_hop1(
    const float* __restrict__ adj, const float* __restrict__ x,
    const float* __restrict__ W, const float* __restrict__ bias,
    u16* __restrict__ y1, u16* __restrict__ ell, unsigned* __restrict__ cnt) {
    extern __shared__ char dyn_pad[];          // occupancy throttle (unused)
    __shared__ u16   raw[4][64 * LCAP];
    __shared__ u16   sIdx[4][CAP];
    __shared__ float sNeigh[4][UU];
    __shared__ float sX1[4][UU];

    const int tid  = threadIdx.x;
    const int wave = tid >> 6;
    const int lane = tid & 63;
    const int rowBase = blockIdx.x * 4;
    const int row  = rowBase + wave;

    // ---- phase 1: pipelined slotted scan (reads adj exactly once, nt 16B)
    const uv4* rowp = reinterpret_cast<const uv4*>(adj + (size_t)row * NN);
    u16* myraw = &raw[wave][lane * LCAP];
    int myCnt = 0;

    uv4 c0 = __builtin_nontemporal_load(&rowp[0 * 64 + lane]);
    uv4 c1 = __builtin_nontemporal_load(&rowp[1 * 64 + lane]);
    uv4 c2 = __builtin_nontemporal_load(&rowp[2 * 64 + lane]);
    uv4 c3 = __builtin_nontemporal_load(&rowp[3 * 64 + lane]);

    for (int b = 0; b < 16; ++b) {
        uv4 n0 = c0, n1 = c1, n2 = c2, n3 = c3;
        if (b < 15) {                                   // prefetch next batch
            const uv4* nb = rowp + (size_t)(b + 1) * 256 + lane;
            n0 = __builtin_nontemporal_load(nb + 0 * 64);
            n1 = __builtin_nontemporal_load(nb + 1 * 64);
            n2 = __builtin_nontemporal_load(nb + 2 * 64);
            n3 = __builtin_nontemporal_load(nb + 3 * 64);
        }
        const uv4 vv[4] = {c0, c1, c2, c3};
#pragma unroll
        for (int j = 0; j < 4; ++j) {
            const unsigned colBase = (unsigned)(((b * 4 + j) * 64 + lane) * 4);
            const unsigned vals[4] = {vv[j].x, vv[j].y, vv[j].z, vv[j].w};
#pragma unroll
            for (int e = 0; e < 4; ++e) {
                if (vals[e] != 0u) {                  // exact 0.0f vs 1.0f bits
                    if (myCnt < LCAP) myraw[myCnt] = (u16)(colBase + e);
                    ++myCnt;
                }
            }
        }
        c0 = n0; c1 = n1; c2 = n2; c3 = n3;
    }
    if (myCnt > LCAP) myCnt = LCAP;               // overflow prob ~1e-9

    // ---- phase 1b: wave exclusive prefix-sum + compaction
    int pre = myCnt;
#pragma unroll
    for (int d = 1; d < 64; d <<= 1) {
        int t = __shfl_up(pre, d);
        if (lane >= d) pre += t;
    }
    const int excl  = pre - myCnt;
    const int total = __shfl(pre, 63);
    const int c = (total < CAP) ? total : CAP;
    if (lane == 0) cnt[row] = (unsigned)c;

    for (int i = 0; i < myCnt; ++i) {
        const int pos = excl + i;
        if (pos < CAP) sIdx[wave][pos] = myraw[i];
    }

    // mirror ELL to global for hop2 (per-wave LDS, no barrier needed)
    for (int p = lane; p < c; p += 64) ell[(size_t)row * CAP + p] = sIdx[wave][p];

    // ---- phase 2: gather (same wave built sIdx -> no barrier needed)
    const int half = lane >> 5;
    const int sl   = lane & 31;
    float4 acc = gather_row_sum_f32(x, sIdx[wave], c, half, sl);
    if (half == 0) *reinterpret_cast<float4*>(&sNeigh[wave][sl * 4]) = acc;
    __syncthreads();

    // ---- phase 3: x1 = swish(neigh@W + b) -> sX1 (block-cooperative)
    const int u = tid & 127;
    const int g = tid >> 7;            // rows 2g, 2g+1
    {
        const float bu = bias[u];
        float f0 = bu, f1 = bu;
        for (int v = 0; v < UU; ++v) {
            const float w = W[v * UU + u];          // coalesced, L1/L2-resident
            f0 += sNeigh[2 * g + 0][v] * w;         // LDS broadcast (uniform v)
            f1 += sNeigh[2 * g + 1][v] * w;
        }
        sX1[2 * g + 0][u] = f0 / (1.0f + __expf(-f0));
        sX1[2 * g + 1][u] = f1 / (1.0f + __expf(-f1));
    }
    __syncthreads();

    // ---- phase 4: y1 = x1 @ W -> bf16 (W reads identical to phase 3, L1-hot)
    {
        float y0 = 0.f, yv1 = 0.f;
        for (int v = 0; v < UU; ++v) {
            const float w = W[v * UU + u];
            y0  += sX1[2 * g + 0][v] * w;
            yv1 += sX1[2 * g + 1][v] * w;
        }
        y1[(size_t)(rowBase + 2 * g + 0) * UU + u] =
            __bfloat16_as_ushort(__float2bfloat16(y0));
        y1[(size_t)(rowBase + 2 * g + 1) * UU + u] =
            __bfloat16_as_ushort(__float2bfloat16(yv1));
    }
    (void)dyn_pad;
}

// ---------------------------------------------------------------------------
// Kernel B: hop2-lite = gather-sum(y1) + bias + swish -> fp32 out.
// One wave per row, no barrier, no GEMM, no W. 4-way k-parallel bf16 gather
// (16 lanes x 16B = one 256B bf16 row per k-slot), all 8 loads in flight.
// ---------------------------------------------------------------------------
__global__ __launch_bounds__(256) void hop2_lite(const u16* __restrict__ y1,
                                                 const u16* __restrict__ ell,
                                                 const unsigned* __restrict__ cnt,
                                                 const float* __restrict__ bias,
                                                 float* __restrict__ out) {
    __shared__ u16 sIdx[4][CAP];

    const int tid  = threadIdx.x;
    const int wave = tid >> 6;
    const int lane = tid & 63;
    const int row  = blockIdx.x * 4 + wave;

    const int c = (int)cnt[row];
    const ushort2* ellRow = reinterpret_cast<const ushort2*>(ell + (size_t)row * CAP);
    reinterpret_cast<ushort2*>(sIdx[wave])[lane] = ellRow[lane];

    const int q = lane >> 4;       // k-slot 0..3
    const int s = lane & 15;       // features s*8 .. s*8+7
    float a[8] = {0.f, 0.f, 0.f, 0.f, 0.f, 0.f, 0.f, 0.f};
#pragma unroll 8
    for (int k = q; k < c; k += 4) {
        const int j = sIdx[wave][k];                        // LDS broadcast
        const uv4 v = *reinterpret_cast<const uv4*>(y1 + (size_t)j * UU + s * 8);
        const unsigned d[4] = {v.x, v.y, v.z, v.w};
#pragma unroll
        for (int m = 0; m < 4; ++m) {
            a[2 * m]     += __uint_as_float(d[m] << 16);
            a[2 * m + 1] += __uint_as_float(d[m] & 0xffff0000u);
        }
    }
#pragma unroll
    for (int m = 0; m < 8; ++m) {
        a[m] += __shfl_xor(a[m], 16);
        a[m] += __shfl_xor(a[m], 32);
    }
    if (q == 0) {
        const float4 b0 = reinterpret_cast<const float4*>(bias)[s * 2];
        const float4 b1 = reinterpret_cast<const float4*>(bias)[s * 2 + 1];
        const float bb[8] = {b0.x, b0.y, b0.z, b0.w, b1.x, b1.y, b1.z, b1.w};
        float o[8];
#pragma unroll
        for (int m = 0; m < 8; ++m) {
            const float p = a[m] + bb[m];
            o[m] = p / (1.0f + __expf(-p));
        }
        float4 o0 = {o[0], o[1], o[2], o[3]};
        float4 o1 = {o[4], o[5], o[6], o[7]};
        *reinterpret_cast<float4*>(out + (size_t)row * UU + s * 8)     = o0;
        *reinterpret_cast<float4*>(out + (size_t)row * UU + s * 8 + 4) = o1;
    }
}

// ---------------------------------------------------------------------------
extern "C" void kernel_launch(void* const* d_in, const int* in_sizes, int n_in,
                              void* d_out, int out_size, void* d_ws, size_t ws_size,
                              hipStream_t stream) {
    const float* x   = (const float*)d_in[0];   // [N, U]
    const float* adj = (const float*)d_in[1];   // [N, N]
    const float* W   = (const float*)d_in[2];   // [U, U]
    const float* b   = (const float*)d_in[3];   // [U]
    float* out = (float*)d_out;                 // [N, U] fp32

    char* ws = (char*)d_ws;
    u16*      y1  = (u16*)(ws);                                    // 4 MB
    u16*      ell = (u16*)(ws + (size_t)4 * 1024 * 1024);          // 4 MB
    unsigned* cnt = (unsigned*)(ws + (size_t)8 * 1024 * 1024);     // 64 KB

    // 30 KB dynamic LDS -> ~4 blocks/CU: halves concurrent HBM row-streams.
    fused_sparsify_hop1<<<NN / 4, 256, 30 * 1024, stream>>>(adj, x, W, b, y1, ell, cnt);
    hop2_lite<<<NN / 4, 256, 0, stream>>>(y1, ell, cnt, b, out);
}

// Round 14
// 214.709 us; speedup vs baseline: 1.0543x; 1.0543x over previous
//
#include <hip/hip_runtime.h>
#include <hip/hip_bf16.h>
#include <stdint.h>

#define NN 16384
#define UU 128
#define CAP 128
#define LCAP 8               // per-lane slot capacity in the scan

typedef unsigned short u16;
typedef unsigned int uv4 __attribute__((ext_vector_type(4)));  // nt-load-able

// Gather-sum of fp32 x-rows listed in sIdx[0..c): 2-way k-parallel (wave
// halves), float4 per lane (32 lanes * 16B = one 512B row per k-slot).
__device__ __forceinline__ float4 gather_row_sum_f32(const float* __restrict__ src,
                                                     const u16* sIdx, int c,
                                                     int half, int sl) {
    float4 acc = {0.f, 0.f, 0.f, 0.f};
#pragma unroll 8
    for (int k = half; k < c; k += 2) {
        const int j = sIdx[k];                                  // LDS broadcast
        const float4 v = *reinterpret_cast<const float4*>(src + (size_t)j * UU + sl * 4);
        acc.x += v.x; acc.y += v.y; acc.z += v.z; acc.w += v.w;
    }
    acc.x += __shfl_xor(acc.x, 32);
    acc.y += __shfl_xor(acc.y, 32);
    acc.z += __shfl_xor(acc.z, 32);
    acc.w += __shfl_xor(acc.w, 32);
    return acc;
}

// ---------------------------------------------------------------------------
// Kernel A: fused sparsify + hop1 + y1-precompute (R12 body; scan pipeline
// deepened to 2 batches ahead = 8 x 1KB loads in flight per wave, same VGPRs).
// ---------------------------------------------------------------------------
__global__ __launch_bounds__(256) void fused_sparsify_hop1(
    const float* __restrict__ adj, const float* __restrict__ x,
    const float* __restrict__ W, const float* __restrict__ bias,
    u16* __restrict__ y1, u16* __restrict__ ell, unsigned* __restrict__ cnt) {
    __shared__ u16   raw[4][64 * LCAP];
    __shared__ u16   sIdx[4][CAP];
    __shared__ float sNeigh[4][UU];
    __shared__ float sX1[4][UU];

    const int tid  = threadIdx.x;
    const int wave = tid >> 6;
    const int lane = tid & 63;
    const int rowBase = blockIdx.x * 4;
    const int row  = rowBase + wave;

    // ---- phase 1: slotted scan, 2-batch-deep pipeline (8 loads in flight)
    const uv4* rowp = reinterpret_cast<const uv4*>(adj + (size_t)row * NN);
    u16* myraw = &raw[wave][lane * LCAP];
    int myCnt = 0;

    // batch = 4 x uv4 per lane (wave covers 4KB); 16 batches per row.
    uv4 a0 = __builtin_nontemporal_load(&rowp[0 * 256 + 0 * 64 + lane]);
    uv4 a1 = __builtin_nontemporal_load(&rowp[0 * 256 + 1 * 64 + lane]);
    uv4 a2 = __builtin_nontemporal_load(&rowp[0 * 256 + 2 * 64 + lane]);
    uv4 a3 = __builtin_nontemporal_load(&rowp[0 * 256 + 3 * 64 + lane]);
    uv4 b0 = __builtin_nontemporal_load(&rowp[1 * 256 + 0 * 64 + lane]);
    uv4 b1 = __builtin_nontemporal_load(&rowp[1 * 256 + 1 * 64 + lane]);
    uv4 b2 = __builtin_nontemporal_load(&rowp[1 * 256 + 2 * 64 + lane]);
    uv4 b3 = __builtin_nontemporal_load(&rowp[1 * 256 + 3 * 64 + lane]);

#define PROCESS_BATCH(R0, R1, R2, R3, BB)                                       \
    {                                                                           \
        const uv4 vv[4] = {R0, R1, R2, R3};                                     \
        _Pragma("unroll")                                                       \
        for (int j = 0; j < 4; ++j) {                                           \
            const unsigned colBase = (unsigned)((((BB) * 4 + j) * 64 + lane) * 4); \
            const unsigned vals[4] = {vv[j].x, vv[j].y, vv[j].z, vv[j].w};      \
            _Pragma("unroll")                                                   \
            for (int e = 0; e < 4; ++e) {                                       \
                if (vals[e] != 0u) {                                            \
                    if (myCnt < LCAP) myraw[myCnt] = (u16)(colBase + e);        \
                    ++myCnt;                                                    \
                }                                                               \
            }                                                                   \
        }                                                                       \
    }

    for (int bb = 0; bb < 16; bb += 2) {
        PROCESS_BATCH(a0, a1, a2, a3, bb);
        if (bb + 2 < 16) {
            const uv4* nb = rowp + (size_t)(bb + 2) * 256 + lane;
            a0 = __builtin_nontemporal_load(nb + 0 * 64);
            a1 = __builtin_nontemporal_load(nb + 1 * 64);
            a2 = __builtin_nontemporal_load(nb + 2 * 64);
            a3 = __builtin_nontemporal_load(nb + 3 * 64);
        }
        PROCESS_BATCH(b0, b1, b2, b3, bb + 1);
        if (bb + 3 < 16) {
            const uv4* nb = rowp + (size_t)(bb + 3) * 256 + lane;
            b0 = __builtin_nontemporal_load(nb + 0 * 64);
            b1 = __builtin_nontemporal_load(nb + 1 * 64);
            b2 = __builtin_nontemporal_load(nb + 2 * 64);
            b3 = __builtin_nontemporal_load(nb + 3 * 64);
        }
    }
#undef PROCESS_BATCH

    if (myCnt > LCAP) myCnt = LCAP;               // overflow prob ~1e-9

    // ---- phase 1b: wave exclusive prefix-sum + compaction
    int pre = myCnt;
#pragma unroll
    for (int d = 1; d < 64; d <<= 1) {
        int t = __shfl_up(pre, d);
        if (lane >= d) pre += t;
    }
    const int excl  = pre - myCnt;
    const int total = __shfl(pre, 63);
    const int c = (total < CAP) ? total : CAP;
    if (lane == 0) cnt[row] = (unsigned)c;

    for (int i = 0; i < myCnt; ++i) {
        const int pos = excl + i;
        if (pos < CAP) sIdx[wave][pos] = myraw[i];
    }

    // mirror ELL to global for hop2 (per-wave LDS, no barrier needed)
    for (int p = lane; p < c; p += 64) ell[(size_t)row * CAP + p] = sIdx[wave][p];

    // ---- phase 2: gather (same wave built sIdx -> no barrier needed)
    const int half = lane >> 5;
    const int sl   = lane & 31;
    float4 acc = gather_row_sum_f32(x, sIdx[wave], c, half, sl);
    if (half == 0) *reinterpret_cast<float4*>(&sNeigh[wave][sl * 4]) = acc;
    __syncthreads();

    // ---- phase 3: x1 = swish(neigh@W + b) -> sX1 (block-cooperative)
    const int u = tid & 127;
    const int g = tid >> 7;            // rows 2g, 2g+1
    {
        const float bu = bias[u];
        float f0 = bu, f1 = bu;
        for (int v = 0; v < UU; ++v) {
            const float w = W[v * UU + u];          // coalesced, L1/L2-resident
            f0 += sNeigh[2 * g + 0][v] * w;         // LDS broadcast (uniform v)
            f1 += sNeigh[2 * g + 1][v] * w;
        }
        sX1[2 * g + 0][u] = f0 / (1.0f + __expf(-f0));
        sX1[2 * g + 1][u] = f1 / (1.0f + __expf(-f1));
    }
    __syncthreads();

    // ---- phase 4: y1 = x1 @ W -> bf16 (W reads identical to phase 3, L1-hot)
    {
        float y0 = 0.f, yv1 = 0.f;
        for (int v = 0; v < UU; ++v) {
            const float w = W[v * UU + u];
            y0  += sX1[2 * g + 0][v] * w;
            yv1 += sX1[2 * g + 1][v] * w;
        }
        y1[(size_t)(rowBase + 2 * g + 0) * UU + u] =
            __bfloat16_as_ushort(__float2bfloat16(y0));
        y1[(size_t)(rowBase + 2 * g + 1) * UU + u] =
            __bfloat16_as_ushort(__float2bfloat16(yv1));
    }
}

// ---------------------------------------------------------------------------
// Kernel B: hop2-lite = gather-sum(y1) + bias + swish -> fp32 out.
// One wave per row, no barrier, no GEMM, no W. 4-way k-parallel bf16 gather
// (16 lanes x 16B = one 256B bf16 row per k-slot), all 8 loads in flight.
// ---------------------------------------------------------------------------
__global__ __launch_bounds__(256) void hop2_lite(const u16* __restrict__ y1,
                                                 const u16* __restrict__ ell,
                                                 const unsigned* __restrict__ cnt,
                                                 const float* __restrict__ bias,
                                                 float* __restrict__ out) {
    __shared__ u16 sIdx[4][CAP];

    const int tid  = threadIdx.x;
    const int wave = tid >> 6;
    const int lane = tid & 63;
    const int row  = blockIdx.x * 4 + wave;

    const int c = (int)cnt[row];
    const ushort2* ellRow = reinterpret_cast<const ushort2*>(ell + (size_t)row * CAP);
    reinterpret_cast<ushort2*>(sIdx[wave])[lane] = ellRow[lane];

    const int q = lane >> 4;       // k-slot 0..3
    const int s = lane & 15;       // features s*8 .. s*8+7
    float a[8] = {0.f, 0.f, 0.f, 0.f, 0.f, 0.f, 0.f, 0.f};
#pragma unroll 8
    for (int k = q; k < c; k += 4) {
        const int j = sIdx[wave][k];                        // LDS broadcast
        const uv4 v = *reinterpret_cast<const uv4*>(y1 + (size_t)j * UU + s * 8);
        const unsigned d[4] = {v.x, v.y, v.z, v.w};
#pragma unroll
        for (int m = 0; m < 4; ++m) {
            a[2 * m]     += __uint_as_float(d[m] << 16);
            a[2 * m + 1] += __uint_as_float(d[m] & 0xffff0000u);
        }
    }
#pragma unroll
    for (int m = 0; m < 8; ++m) {
        a[m] += __shfl_xor(a[m], 16);
        a[m] += __shfl_xor(a[m], 32);
    }
    if (q == 0) {
        const float4 b0 = reinterpret_cast<const float4*>(bias)[s * 2];
        const float4 b1 = reinterpret_cast<const float4*>(bias)[s * 2 + 1];
        const float bb[8] = {b0.x, b0.y, b0.z, b0.w, b1.x, b1.y, b1.z, b1.w};
        float o[8];
#pragma unroll
        for (int m = 0; m < 8; ++m) {
            const float p = a[m] + bb[m];
            o[m] = p / (1.0f + __expf(-p));
        }
        float4 o0 = {o[0], o[1], o[2], o[3]};
        float4 o1 = {o[4], o[5], o[6], o[7]};
        *reinterpret_cast<float4*>(out + (size_t)row * UU + s * 8)     = o0;
        *reinterpret_cast<float4*>(out + (size_t)row * UU + s * 8 + 4) = o1;
    }
}

// ---------------------------------------------------------------------------
extern "C" void kernel_launch(void* const* d_in, const int* in_sizes, int n_in,
                              void* d_out, int out_size, void* d_ws, size_t ws_size,
                              hipStream_t stream) {
    const float* x   = (const float*)d_in[0];   // [N, U]
    const float* adj = (const float*)d_in[1];   // [N, N]
    const float* W   = (const float*)d_in[2];   // [U, U]
    const float* b   = (const float*)d_in[3];   // [U]
    float* out = (float*)d_out;                 // [N, U] fp32

    char* ws = (char*)d_ws;
    u16*      y1  = (u16*)(ws);                                    // 4 MB
    u16*      ell = (u16*)(ws + (size_t)4 * 1024 * 1024);          // 4 MB
    unsigned* cnt = (unsigned*)(ws + (size_t)8 * 1024 * 1024);     // 64 KB

    fused_sparsify_hop1<<<NN / 4, 256, 0, stream>>>(adj, x, W, b, y1, ell, cnt);
    hop2_lite<<<NN / 4, 256, 0, stream>>>(y1, ell, cnt, b, out);
}